// Round 5
// baseline (370.745 us; speedup 1.0000x reference)
//
#include <hip/hip_runtime.h>

// Sorted-segment product: out[i] = prod_{j: csr[j]==i} x[ptrs[j]], empty -> 0.
//
// R5: occupancy fix. Counters show 64KB-LDS blocks only ever get ~16
// waves/CU resident (R3 44%, R4 46%) -> barrier-delimited window phases
// expose L2 latency (2.18 TB/s effective vs 3.67 achievable). Shrink to
// 32KB LDS blocks (BLK=512, EPT=16, MSC=8192) and 1024 persistent blocks
// so ~4 independent blocks/CU hide each other's barrier stalls.
// Byte counts invariant: still 2 sweeps of x per XCD (256MB fills),
// same ptrs/csr streaming, same register footprint (44 VGPR, no spill).

#define EPT       16              // edges per thread (pt[16]+g[16] = 32 VGPRs)
#define EPT_SHIFT 4
#define BLK       512             // threads per block (8 waves)
#define MSC       (BLK * EPT)     // 8192 edges per superchunk -> 32KB LDS
#define NBLK      1024            // persistent blocks (~4 per CU)
#define WSHIFT    18              // window = 2^18 floats = 1 MB

__global__ __launch_bounds__(BLK, 8) void prodseg_main(
    const float* __restrict__ x,
    const int*   __restrict__ ptrs,
    const int*   __restrict__ csr,
    float*       __restrict__ out,
    int E, int S, int F /* # full superchunks */, int nwin)
{
    __shared__ float gbuf[MSC];   // column-major: edge (t,k) -> gbuf[k*BLK + t]
    const int t = threadIdx.x;
    const int ngen = (F + (int)gridDim.x - 1) / (int)gridDim.x;

    for (int gen = 0; gen < ngen; ++gen) {
        int sc = gen * (int)gridDim.x + (int)blockIdx.x;
        if (sc >= F) break;                    // block-uniform exit
        const int sbase = sc * MSC;
        const int gbase = sbase + t * EPT;

        // ---- stage my 16 ptrs into registers (vectorized, aligned) ----
        int pt[EPT];
        {
            const int4* p4 = reinterpret_cast<const int4*>(ptrs + gbase);
            #pragma unroll
            for (int i = 0; i < EPT / 4; ++i) {
                int4 v = p4[i];
                pt[4*i+0] = v.x; pt[4*i+1] = v.y;
                pt[4*i+2] = v.z; pt[4*i+3] = v.w;
            }
        }

        // ---- window-phased gather ----
        float g[EPT];
        for (int w = 0; w < nwin; ++w) {
            // 1) predicated loads only — independent, all issue (MLP)
            #pragma unroll
            for (int k = 0; k < EPT; ++k)
                if ((pt[k] >> WSHIFT) == w) g[k] = x[pt[k]];
            // 2) mirror to LDS for cross-thread run walks
            #pragma unroll
            for (int k = 0; k < EPT; ++k)
                if ((pt[k] >> WSHIFT) == w) gbuf[k * BLK + t] = g[k];
            // keep this block's waves phase-aligned (L2 locality); other
            // blocks on the CU hide the barrier stall. Final one orders
            // gbuf writes before product-phase reads.
            __syncthreads();
        }

        // ---- product phase (run ownership, exact) ----
        int prev = (gbase == 0) ? -1 : csr[gbase - 1];
        const int4* c4 = reinterpret_cast<const int4*>(csr + gbase);
        int cur = 0; bool own = false; float prod = 1.0f;
        #pragma unroll
        for (int i = 0; i < EPT / 4; ++i) {
            int4 c = c4[i];
            int sv[4] = {c.x, c.y, c.z, c.w};
            #pragma unroll
            for (int j = 0; j < 4; ++j) {
                const int k = 4 * i + j;
                int sg = sv[j];
                if (k == 0) {
                    cur = sg; own = (sg != prev);
                    prod = own ? g[0] : 1.0f;
                    if (own)
                        for (int q = prev + 1; q < cur; ++q) out[q] = 0.0f;
                } else {
                    if (sg == cur) {
                        prod *= g[k];          // harmless if !own (never stored)
                    } else {
                        if (own) out[cur] = prod;
                        for (int q = cur + 1; q < sg; ++q) out[q] = 0.0f;
                        cur = sg; own = true; prod = g[k];
                    }
                }
            }
        }
        // final run: walk forward; in-superchunk values come from LDS
        if (own) {
            int idx = gbase + EPT;
            while (idx < E) {
                if (csr[idx] != cur) break;
                float v;
                int local = idx - sbase;
                if (local < MSC)
                    v = gbuf[(local & (EPT - 1)) * BLK + (local >> EPT_SHIFT)];
                else
                    v = x[ptrs[idx]];
                prod *= v; ++idx;
            }
            out[cur] = prod;
            if (idx == E)
                for (int q = cur + 1; q < S; ++q) out[q] = 0.0f;
        }
        __syncthreads();   // protect gbuf before next generation
    }
}

// Generic tail (E % MSC != 0) — R1-proven logic; not launched for E = 2^24.
#define TK 8
__global__ __launch_bounds__(256) void prodseg_tail(
    const float* __restrict__ x,
    const int*   __restrict__ ptrs,
    const int*   __restrict__ csr,
    float*       __restrict__ out,
    int E0, int E, int S)
{
    int t = blockIdx.x * blockDim.x + threadIdx.x;
    int base = E0 + t * TK;
    if (base >= E) return;
    int prev = (base == 0) ? -1 : csr[base - 1];
    int n = (base + TK <= E) ? TK : (E - base);

    int cur = 0; bool own = false; float prod = 1.0f;
    for (int k = 0; k < n; ++k) {
        int sg = csr[base + k];
        float gv = x[ptrs[base + k]];
        if (k == 0) {
            cur = sg; own = (sg != prev);
            prod = own ? gv : 1.0f;
            if (own) for (int q = prev + 1; q < cur; ++q) out[q] = 0.0f;
        } else if (sg == cur) {
            prod *= gv;
        } else {
            if (own) out[cur] = prod;
            for (int q = cur + 1; q < sg; ++q) out[q] = 0.0f;
            cur = sg; own = true; prod = gv;
        }
    }
    if (own) {
        int idx = base + n;
        while (idx < E && csr[idx] == cur) { prod *= x[ptrs[idx]]; ++idx; }
        out[cur] = prod;
        if (idx == E) for (int q = cur + 1; q < S; ++q) out[q] = 0.0f;
    }
}

extern "C" void kernel_launch(void* const* d_in, const int* in_sizes, int n_in,
                              void* d_out, int out_size, void* d_ws, size_t ws_size,
                              hipStream_t stream) {
    const float* x    = (const float*)d_in[0];
    const int*   ptrs = (const int*)d_in[1];
    const int*   csr  = (const int*)d_in[2];
    float*       out  = (float*)d_out;
    int N = in_sizes[0];
    int E = in_sizes[1];
    int S = out_size;

    int F  = E / MSC;                                   // full superchunks
    int E0 = F * MSC;
    int nwin = (N + (1 << WSHIFT) - 1) >> WSHIFT;       // 16 for N = 2^22

    if (F > 0)
        prodseg_main<<<NBLK, BLK, 0, stream>>>(x, ptrs, csr, out, E, S, F, nwin);
    if (E0 < E) {
        int nt = (E - E0 + TK - 1) / TK;
        prodseg_tail<<<(nt + 255) / 256, 256, 0, stream>>>(x, ptrs, csr, out, E0, E, S);
    }
}